// Round 11
// baseline (171.765 us; speedup 1.0000x reference)
//
#include <hip/hip_runtime.h>

typedef __bf16 bf16;
typedef __bf16 bf16x8 __attribute__((ext_vector_type(8)));
typedef __bf16 bf16x4 __attribute__((ext_vector_type(4)));
typedef __bf16 bf16x2 __attribute__((ext_vector_type(2)));
typedef float f32x4 __attribute__((ext_vector_type(4)));
typedef unsigned int u32;
typedef unsigned int u32x4 __attribute__((ext_vector_type(4)));

#define BS 4
#define SEQ 2048
#define DM 1024
#define NH 16
#define DKH 64
#define NITEMS 1024  // 4 b * 16 h * 16 q-blocks of 128 rows

__device__ __forceinline__ void gload_lds16(const void* g, void* l) {
  __builtin_amdgcn_global_load_lds(
      (const __attribute__((address_space(1))) unsigned int*)g,
      (__attribute__((address_space(3))) unsigned int*)l, 16, 0, 0);
}

// ---------------------------------------------------------------------------
// W f32 -> bf16; block 0 also builds the LPT batch permutation (len desc)
// and zeroes the single ticket counter (runs first on every replay).
// ---------------------------------------------------------------------------
__global__ __launch_bounds__(256) void wconv(const float* __restrict__ W,
                                             bf16* __restrict__ Wb,
                                             const int* __restrict__ lens,
                                             int* __restrict__ perm,
                                             int* __restrict__ ctr) {
  const int i = (blockIdx.x * 256 + threadIdx.x) * 4;
  f32x4 v = *(const f32x4*)(W + i);
  bf16x4 h;
#pragma unroll
  for (int j = 0; j < 4; ++j) h[j] = (bf16)v[j];
  *(bf16x4*)(Wb + i) = h;
  if (blockIdx.x == 0 && threadIdx.x == 0) {
    int p[4] = {0, 1, 2, 3};
    int l[4] = {lens[0], lens[1], lens[2], lens[3]};
#pragma unroll
    for (int a = 0; a < 3; ++a)
#pragma unroll
      for (int c = 0; c < 3 - a; ++c)
        if (l[p[c + 1]] > l[p[c]]) { int tmp = p[c]; p[c] = p[c + 1]; p[c + 1] = tmp; }
#pragma unroll
    for (int a = 0; a < 4; ++a) perm[a] = p[a];
    *ctr = 0;
  }
}

// ---------------------------------------------------------------------------
// Projection: Y = scale * (X @ W^T). XCD-chunked flat grid + T2 swizzles
// (round 7, proven). Q-scale folds log2(e): scale_q = log2(e)/sqrt(1024).
// ---------------------------------------------------------------------------
__global__ __launch_bounds__(256) void proj_gemm(
    const float* __restrict__ Qin, const float* __restrict__ Kin,
    const float* __restrict__ Vin, const bf16* __restrict__ Wb,
    bf16* __restrict__ qw, bf16* __restrict__ kw, bf16* __restrict__ vw) {
  __shared__ bf16 As[128 * 64];
  __shared__ bf16 Bs[128 * 64];
  const int wid = ((blockIdx.x & 7) * 192) + (blockIdx.x >> 3);  // XCD-chunked
  const int n0 = (wid & 7) * 128;
  const int mz = wid >> 3;        // z*64 + m
  const int m0 = (mz & 63) * 128;
  const int z = mz >> 6;
  const float* X = (z == 0) ? Qin : (z == 1) ? Kin : Vin;
  bf16* Y = (z == 0) ? qw : (z == 1) ? kw : vw;
  // q: 1/sqrt(1024) * log2(e)  (exp2-domain softmax)
  const float scale = (z == 0) ? 0.045084220027780095f : 1.0f;

  const int tid = threadIdx.x;
  const int lane = tid & 63;
  const int w = tid >> 6;
  const int wm = w >> 1, wn = w & 1;
  const int lr = lane & 15;
  const int lg = lane >> 4;
  const int rsw = (lr & 7) << 4;        // read-side XOR swizzle
  const int srow = tid >> 3;            // staging row (0..31)
  const int swz = (srow & 7) << 4;      // write-side XOR swizzle
  const int sc8 = (tid & 7) * 8;        // element col (8 per lane)
  const int scolb = ((tid & 7) * 16) ^ swz;  // inverse-swz source byte col (Bs)

  f32x4 acc[4][4];
#pragma unroll
  for (int m = 0; m < 4; ++m)
#pragma unroll
    for (int n = 0; n < 4; ++n) acc[m][n] = (f32x4){0.f, 0.f, 0.f, 0.f};

  for (int k0 = 0; k0 < DM; k0 += 64) {
    __syncthreads();
    // A: f32 global (linear) -> regs -> cvt -> swizzled ds_write_b128
#pragma unroll
    for (int q = 0; q < 4; ++q) {
      const float* src = X + (size_t)(m0 + q * 32 + srow) * DM + k0 + sc8;
      f32x4 f0 = *(const f32x4*)src;
      f32x4 f1 = *(const f32x4*)(src + 4);
      bf16x8 h;
#pragma unroll
      for (int i = 0; i < 4; ++i) { h[i] = (bf16)f0[i]; h[4 + i] = (bf16)f1[i]; }
      *(bf16x8*)((char*)As + (q * 32 + srow) * 128 + (((tid & 7) * 16) ^ swz)) = h;
    }
    // B: bf16 global (inverse-swizzled source col) -> linear LDS dest
#pragma unroll
    for (int q = 0; q < 4; ++q)
      gload_lds16((const char*)(Wb + (size_t)(n0 + q * 32 + srow) * DM + k0) + scolb,
                  (char*)Bs + q * 4096 + tid * 16);
    __syncthreads();

#pragma unroll
    for (int kk = 0; kk < 2; ++kk) {
      bf16x8 af[4], bfr[4];
#pragma unroll
      for (int m = 0; m < 4; ++m)
        af[m] = *(const bf16x8*)((const char*)As + (wm * 64 + m * 16 + lr) * 128 +
                                 ((kk * 64 + lg * 16) ^ rsw));
#pragma unroll
      for (int n = 0; n < 4; ++n)
        bfr[n] = *(const bf16x8*)((const char*)Bs + (wn * 64 + n * 16 + lr) * 128 +
                                  ((kk * 64 + lg * 16) ^ rsw));
#pragma unroll
      for (int m = 0; m < 4; ++m)
#pragma unroll
        for (int n = 0; n < 4; ++n)
          acc[m][n] = __builtin_amdgcn_mfma_f32_16x16x32_bf16(af[m], bfr[n], acc[m][n], 0, 0, 0);
    }
  }

#pragma unroll
  for (int m = 0; m < 4; ++m)
#pragma unroll
    for (int n = 0; n < 4; ++n)
#pragma unroll
      for (int j = 0; j < 4; ++j) {
        const int row = m0 + wm * 64 + m * 16 + lg * 4 + j;
        const int col = n0 + wn * 64 + n * 16 + lr;
        Y[(size_t)row * DM + col] = (bf16)(acc[m][n][j] * scale);
      }
}

// ---------------------------------------------------------------------------
// V transpose (unchanged).
// ---------------------------------------------------------------------------
__global__ __launch_bounds__(256) void vtrans(const bf16* __restrict__ v,
                                              bf16* __restrict__ vt) {
  __shared__ bf16 t[64][72];
  const int b = blockIdx.z, h = blockIdx.y, s0 = blockIdx.x * 64;
  const int tid = threadIdx.x;
#pragma unroll
  for (int p = 0; p < 2; ++p) {
    const int row = p * 32 + (tid >> 3);
    const int c = (tid & 7) * 8;
    bf16x8 d = *(const bf16x8*)(v + ((size_t)b * SEQ + s0 + row) * DM + h * 64 + c);
#pragma unroll
    for (int i = 0; i < 8; ++i) t[row][c + i] = d[i];
  }
  __syncthreads();
#pragma unroll
  for (int p = 0; p < 2; ++p) {
    const int dk = p * 32 + (tid >> 3);
    const int c = (tid & 7) * 8;
    union { bf16x8 v8; bf16 a[8]; } u;
#pragma unroll
    for (int i = 0; i < 8; ++i) u.a[i] = t[c + i][dk];
    *(bf16x8*)(vt + ((size_t)(b * NH + h) * DKH + dk) * SEQ + s0 + c) = u.v8;
  }
}

// ---------------------------------------------------------------------------
// Flash attention — ROUND 11: KVBLK=128. Stage 128 keys per barrier pair
// (K 16 KB + V 16 KB = 32 KB LDS; occupancy still VGPR-bound at 3 blk/CU),
// then run the proven 64-key compute body twice per staging round (keeps
// s[4]/pk register footprint). Barriers + vmcnt(0) convoys + queue overhead
// per key halve vs round 9. Uniform break skips fully-masked second half.
// Keeps: 8-wave blocks (128 q-rows/item), swapped QK^T, in-register exp2
// softmax, exact defer-rescale, shfl P^T B-frags, O^T accum, LPT queue.
// grid = 768 persistent blocks, block = 512 (8 waves x 16 q-rows).
// ---------------------------------------------------------------------------
__global__ __launch_bounds__(512, 6) void attn_fwd(
    const bf16* __restrict__ qw, const bf16* __restrict__ kw,
    const bf16* __restrict__ vt, const int* __restrict__ lens,
    const int* __restrict__ perm, int* __restrict__ ctr,
    float* __restrict__ out) {
  __shared__ bf16 ks[128 * 64];  // [key 0..127][dk 0..63], 128 B rows
  __shared__ bf16 vs[64 * 128];  // [dk 0..63][key 0..127], 256 B rows
  __shared__ int s_item;
  const int tid = threadIdx.x, lane = tid & 63, w = tid >> 6;  // w = 0..7
  const int lr = lane & 15, lg = lane >> 4;
  const int rsw = (lr & 7) << 4;  // read-side XOR swizzle (row&7 == lr&7)
  const int srow = tid >> 3;      // K staging row (0..63), 8 thr/row
  const int scolb = ((tid & 7) * 16) ^ ((srow & 7) << 4);   // K inv-swz src col
  const int srow2 = tid >> 4;     // V staging row (0..31), 16 thr/row
  const int vscolb = ((tid & 15) * 16) ^ ((srow2 & 7) << 4);  // V inv-swz src col

  for (;;) {
    __syncthreads();  // prior item's LDS reads + s_item consumption done
    if (tid == 0) s_item = atomicAdd(ctr, 1);
    __syncthreads();
    const int item = s_item;
    if (item >= NITEMS) return;

    const int b = perm[item >> 8];  // LPT: 256 items per batch, longest first
    const int h = (item >> 4) & 15;
    const int q0 = (item & 15) * 128;
    const int len = lens[b];
    const int ntiles = (len + 127) >> 7;

    const bf16* kbase = kw + (size_t)b * SEQ * DM + h * 64;
    const bf16* vbase = vt + (size_t)(b * NH + h) * DKH * SEQ;
    // Q[q=lr-row of this wave][dk = lg*8.. (+32)] serves as B-frag directly
    const bf16* qbase = qw + ((size_t)b * SEQ + q0 + w * 16 + lr) * DM + h * 64 + lg * 8;
    const bf16x8 aq0 = *(const bf16x8*)(qbase);
    const bf16x8 aq1 = *(const bf16x8*)(qbase + 32);

    f32x4 acc[4];  // O^T: acc[n][j] = O[q=lr][dk = n*16 + lg*4 + j]
#pragma unroll
    for (int n = 0; n < 4; ++n) acc[n] = (f32x4){0.f, 0.f, 0.f, 0.f};
    float mrow = -1e30f, lrow = 0.f;

    for (int t = 0; t < ntiles; ++t) {
      const int k0 = t << 7;
      __syncthreads();  // prior tile's ks/vs reads complete
      // K: 2 x (512 thr x 16 B) = 16 KB; rows k0..k0+127
#pragma unroll
      for (int q = 0; q < 2; ++q)
        gload_lds16((const char*)(kbase + (size_t)(k0 + q * 64 + srow) * DM) + scolb,
                    (char*)ks + q * 8192 + tid * 16);
      // V: 2 x 8 KB; rows dk 0..63, cols k0..k0+127 (256 B rows)
#pragma unroll
      for (int q = 0; q < 2; ++q)
        gload_lds16((const char*)(vbase + (size_t)(q * 32 + srow2) * SEQ + k0) + vscolb,
                    (char*)vs + q * 8192 + tid * 16);
      __syncthreads();  // vmcnt drained -> tiles readable

      // two 64-key halves per staging round (register footprint of one)
#pragma unroll
      for (int hh = 0; hh < 2; ++hh) {
        const int kb = k0 + hh * 64;
        if (kb >= len) break;  // uniform: whole half masked -> skip

        // ---- S^T = K @ Q^T : s[m][j] = S[key = kb + m*16+lg*4+j][q=lr] ----
        f32x4 s[4];
#pragma unroll
        for (int n = 0; n < 4; ++n) s[n] = (f32x4){0.f, 0.f, 0.f, 0.f};
#pragma unroll
        for (int kk = 0; kk < 2; ++kk) {
          const bf16x8 aqk = kk ? aq1 : aq0;
#pragma unroll
          for (int m = 0; m < 4; ++m) {
            bf16x8 ak = *(const bf16x8*)((const char*)ks +
                                         (hh * 64 + m * 16 + lr) * 128 +
                                         ((kk * 64 + lg * 16) ^ rsw));
            s[m] = __builtin_amdgcn_mfma_f32_16x16x32_bf16(ak, aqk, s[m], 0, 0, 0);
          }
        }
        if (kb + 64 > len) {  // partial half: mask keys >= len
#pragma unroll
          for (int m = 0; m < 4; ++m)
#pragma unroll
            for (int j = 0; j < 4; ++j)
              if (kb + m * 16 + lg * 4 + j >= len) s[m][j] = -1e30f;
        }

        // ---- online softmax (exp2 domain), per-lane scalar state ----
        float tmax = fmaxf(fmaxf(fmaxf(s[0][0], s[0][1]), fmaxf(s[0][2], s[0][3])),
                           fmaxf(fmaxf(s[1][0], s[1][1]), fmaxf(s[1][2], s[1][3])));
        tmax = fmaxf(tmax,
                     fmaxf(fmaxf(fmaxf(s[2][0], s[2][1]), fmaxf(s[2][2], s[2][3])),
                           fmaxf(fmaxf(s[3][0], s[3][1]), fmaxf(s[3][2], s[3][3]))));
        tmax = fmaxf(tmax, __shfl_xor(tmax, 16, 64));
        tmax = fmaxf(tmax, __shfl_xor(tmax, 32, 64));
        if (!__all(tmax <= mrow)) {  // defer-rescale: scl==1 exactly when skipped
          const float mn = fmaxf(mrow, tmax);
          const float scl = exp2f(mrow - mn);
          mrow = mn;
          lrow *= scl;
#pragma unroll
          for (int n = 0; n < 4; ++n) acc[n] *= scl;
        }

        float lsum = 0.f;
#pragma unroll
        for (int m = 0; m < 4; ++m)
#pragma unroll
          for (int j = 0; j < 4; ++j) {
            const float p = exp2f(s[m][j] - mrow);
            s[m][j] = p;
            lsum += p;
          }
        lsum += __shfl_xor(lsum, 16, 64);
        lsum += __shfl_xor(lsum, 32, 64);
        lrow += lsum;

        // ---- pack P to bf16 pairs: pk[m][hh2] = {p[m][2hh2], p[m][2hh2+1]} ----
        u32 pk[4][2];
#pragma unroll
        for (int m = 0; m < 4; ++m)
#pragma unroll
          for (int hh2 = 0; hh2 < 2; ++hh2) {
            bf16x2 tpk;
            tpk[0] = (bf16)s[m][2 * hh2];
            tpk[1] = (bf16)s[m][2 * hh2 + 1];
            pk[m][hh2] = __builtin_bit_cast(u32, tpk);
          }

        // ---- PV: O^T += V^T @ P^T ----
#pragma unroll
        for (int kk = 0; kk < 2; ++kk) {
          u32x4 wv;
#pragma unroll
          for (int w2 = 0; w2 < 4; ++w2) {
            const int src = lr + ((lane & 16) << 1) + ((w2 >> 1) << 4);
            const u32 lo = (u32)__shfl((int)pk[2 * kk][w2 & 1], src, 64);
            const u32 hi = (u32)__shfl((int)pk[2 * kk + 1][w2 & 1], src, 64);
            wv[w2] = (lg & 2) ? hi : lo;
          }
          const bf16x8 bp = __builtin_bit_cast(bf16x8, wv);
#pragma unroll
          for (int n = 0; n < 4; ++n) {
            bf16x8 av = *(const bf16x8*)((const char*)vs + (n * 16 + lr) * 256 +
                                         ((hh * 128 + kk * 64 + lg * 16) ^ rsw));
            acc[n] = __builtin_amdgcn_mfma_f32_16x16x32_bf16(av, bp, acc[n], 0, 0, 0);
          }
        }
      }
    }

    // ---- epilogue: O = acc / lrow; acc[n][j] is contiguous in dk ----
    const float inv = 1.0f / lrow;
    float* obase = out + ((size_t)b * SEQ + q0 + w * 16 + lr) * DM + h * 64 + lg * 4;
#pragma unroll
    for (int n = 0; n < 4; ++n) {
      f32x4 o = acc[n] * inv;
      *(f32x4*)(obase + n * 16) = o;
    }
  }
}

extern "C" void kernel_launch(void* const* d_in, const int* in_sizes, int n_in,
                              void* d_out, int out_size, void* d_ws, size_t ws_size,
                              hipStream_t stream) {
  const float* Q = (const float*)d_in[0];
  const float* K = (const float*)d_in[1];
  const float* V = (const float*)d_in[2];
  const float* W = (const float*)d_in[3];
  const int* lens = (const int*)d_in[4];
  float* out = (float*)d_out;

  char* ws = (char*)d_ws;
  const size_t seg = (size_t)BS * SEQ * DM * sizeof(bf16);  // 16 MiB
  bf16* qw = (bf16*)(ws);
  bf16* kw = (bf16*)(ws + seg);
  bf16* vw = (bf16*)(ws + 2 * seg);
  bf16* vt = (bf16*)(ws + 3 * seg);
  bf16* Wb = (bf16*)(ws + 4 * seg);             // 2 MiB
  int* perm = (int*)(ws + 4 * seg + 0x200000);  // 16 B
  int* ctr = perm + 4;

  wconv<<<dim3((DM * DM) / (256 * 4)), 256, 0, stream>>>(W, Wb, lens, perm, ctr);
  proj_gemm<<<1536, 256, 0, stream>>>(Q, K, V, Wb, qw, kw, vw);
  vtrans<<<dim3(SEQ / 64, NH, BS), 256, 0, stream>>>(vw, vt);
  attn_fwd<<<768, 512, 0, stream>>>(qw, kw, vt, lens, perm, ctr, out);
}

// Round 12
// 164.926 us; speedup vs baseline: 1.0415x; 1.0415x over previous
//
#include <hip/hip_runtime.h>

typedef __bf16 bf16;
typedef __bf16 bf16x8 __attribute__((ext_vector_type(8)));
typedef __bf16 bf16x4 __attribute__((ext_vector_type(4)));
typedef __bf16 bf16x2 __attribute__((ext_vector_type(2)));
typedef float f32x4 __attribute__((ext_vector_type(4)));
typedef unsigned int u32;
typedef unsigned int u32x2 __attribute__((ext_vector_type(2)));

#define BS 4
#define SEQ 2048
#define DM 1024
#define NH 16
#define DKH 64
#define NITEMS 1024  // 4 b * 16 h * 16 q-blocks of 128 rows

__device__ __forceinline__ void gload_lds16(const void* g, void* l) {
  __builtin_amdgcn_global_load_lds(
      (const __attribute__((address_space(1))) unsigned int*)g,
      (__attribute__((address_space(3))) unsigned int*)l, 16, 0, 0);
}

// ---------------------------------------------------------------------------
// W f32 -> bf16; block 0 also builds the LPT batch permutation (len desc)
// and zeroes the single ticket counter (runs first on every replay).
// ---------------------------------------------------------------------------
__global__ __launch_bounds__(256) void wconv(const float* __restrict__ W,
                                             bf16* __restrict__ Wb,
                                             const int* __restrict__ lens,
                                             int* __restrict__ perm,
                                             int* __restrict__ ctr) {
  const int i = (blockIdx.x * 256 + threadIdx.x) * 4;
  f32x4 v = *(const f32x4*)(W + i);
  bf16x4 h;
#pragma unroll
  for (int j = 0; j < 4; ++j) h[j] = (bf16)v[j];
  *(bf16x4*)(Wb + i) = h;
  if (blockIdx.x == 0 && threadIdx.x == 0) {
    int p[4] = {0, 1, 2, 3};
    int l[4] = {lens[0], lens[1], lens[2], lens[3]};
#pragma unroll
    for (int a = 0; a < 3; ++a)
#pragma unroll
      for (int c = 0; c < 3 - a; ++c)
        if (l[p[c + 1]] > l[p[c]]) { int tmp = p[c]; p[c] = p[c + 1]; p[c + 1] = tmp; }
#pragma unroll
    for (int a = 0; a < 4; ++a) perm[a] = p[a];
    *ctr = 0;
  }
}

// ---------------------------------------------------------------------------
// Projection: Y = scale * (X @ W^T). XCD-chunked flat grid + T2 swizzles
// (round 7, proven). Q-scale folds log2(e): scale_q = log2(e)/sqrt(1024).
// ---------------------------------------------------------------------------
__global__ __launch_bounds__(256) void proj_gemm(
    const float* __restrict__ Qin, const float* __restrict__ Kin,
    const float* __restrict__ Vin, const bf16* __restrict__ Wb,
    bf16* __restrict__ qw, bf16* __restrict__ kw, bf16* __restrict__ vw) {
  __shared__ bf16 As[128 * 64];
  __shared__ bf16 Bs[128 * 64];
  const int wid = ((blockIdx.x & 7) * 192) + (blockIdx.x >> 3);  // XCD-chunked
  const int n0 = (wid & 7) * 128;
  const int mz = wid >> 3;        // z*64 + m
  const int m0 = (mz & 63) * 128;
  const int z = mz >> 6;
  const float* X = (z == 0) ? Qin : (z == 1) ? Kin : Vin;
  bf16* Y = (z == 0) ? qw : (z == 1) ? kw : vw;
  // q: 1/sqrt(1024) * log2(e)  (exp2-domain softmax)
  const float scale = (z == 0) ? 0.045084220027780095f : 1.0f;

  const int tid = threadIdx.x;
  const int lane = tid & 63;
  const int w = tid >> 6;
  const int wm = w >> 1, wn = w & 1;
  const int lr = lane & 15;
  const int lg = lane >> 4;
  const int rsw = (lr & 7) << 4;        // read-side XOR swizzle
  const int srow = tid >> 3;            // staging row (0..31)
  const int swz = (srow & 7) << 4;      // write-side XOR swizzle
  const int sc8 = (tid & 7) * 8;        // element col (8 per lane)
  const int scolb = ((tid & 7) * 16) ^ swz;  // inverse-swz source byte col (Bs)

  f32x4 acc[4][4];
#pragma unroll
  for (int m = 0; m < 4; ++m)
#pragma unroll
    for (int n = 0; n < 4; ++n) acc[m][n] = (f32x4){0.f, 0.f, 0.f, 0.f};

  for (int k0 = 0; k0 < DM; k0 += 64) {
    __syncthreads();
    // A: f32 global (linear) -> regs -> cvt -> swizzled ds_write_b128
#pragma unroll
    for (int q = 0; q < 4; ++q) {
      const float* src = X + (size_t)(m0 + q * 32 + srow) * DM + k0 + sc8;
      f32x4 f0 = *(const f32x4*)src;
      f32x4 f1 = *(const f32x4*)(src + 4);
      bf16x8 h;
#pragma unroll
      for (int i = 0; i < 4; ++i) { h[i] = (bf16)f0[i]; h[4 + i] = (bf16)f1[i]; }
      *(bf16x8*)((char*)As + (q * 32 + srow) * 128 + (((tid & 7) * 16) ^ swz)) = h;
    }
    // B: bf16 global (inverse-swizzled source col) -> linear LDS dest
#pragma unroll
    for (int q = 0; q < 4; ++q)
      gload_lds16((const char*)(Wb + (size_t)(n0 + q * 32 + srow) * DM + k0) + scolb,
                  (char*)Bs + q * 4096 + tid * 16);
    __syncthreads();

#pragma unroll
    for (int kk = 0; kk < 2; ++kk) {
      bf16x8 af[4], bfr[4];
#pragma unroll
      for (int m = 0; m < 4; ++m)
        af[m] = *(const bf16x8*)((const char*)As + (wm * 64 + m * 16 + lr) * 128 +
                                 ((kk * 64 + lg * 16) ^ rsw));
#pragma unroll
      for (int n = 0; n < 4; ++n)
        bfr[n] = *(const bf16x8*)((const char*)Bs + (wn * 64 + n * 16 + lr) * 128 +
                                  ((kk * 64 + lg * 16) ^ rsw));
#pragma unroll
      for (int m = 0; m < 4; ++m)
#pragma unroll
        for (int n = 0; n < 4; ++n)
          acc[m][n] = __builtin_amdgcn_mfma_f32_16x16x32_bf16(af[m], bfr[n], acc[m][n], 0, 0, 0);
    }
  }

#pragma unroll
  for (int m = 0; m < 4; ++m)
#pragma unroll
    for (int n = 0; n < 4; ++n)
#pragma unroll
      for (int j = 0; j < 4; ++j) {
        const int row = m0 + wm * 64 + m * 16 + lg * 4 + j;
        const int col = n0 + wn * 64 + n * 16 + lr;
        Y[(size_t)row * DM + col] = (bf16)(acc[m][n][j] * scale);
      }
}

// ---------------------------------------------------------------------------
// V transpose (unchanged).
// ---------------------------------------------------------------------------
__global__ __launch_bounds__(256) void vtrans(const bf16* __restrict__ v,
                                              bf16* __restrict__ vt) {
  __shared__ bf16 t[64][72];
  const int b = blockIdx.z, h = blockIdx.y, s0 = blockIdx.x * 64;
  const int tid = threadIdx.x;
#pragma unroll
  for (int p = 0; p < 2; ++p) {
    const int row = p * 32 + (tid >> 3);
    const int c = (tid & 7) * 8;
    bf16x8 d = *(const bf16x8*)(v + ((size_t)b * SEQ + s0 + row) * DM + h * 64 + c);
#pragma unroll
    for (int i = 0; i < 8; ++i) t[row][c + i] = d[i];
  }
  __syncthreads();
#pragma unroll
  for (int p = 0; p < 2; ++p) {
    const int dk = p * 32 + (tid >> 3);
    const int c = (tid & 7) * 8;
    union { bf16x8 v8; bf16 a[8]; } u;
#pragma unroll
    for (int i = 0; i < 8; ++i) u.a[i] = t[c + i][dk];
    *(bf16x8*)(vt + ((size_t)(b * NH + h) * DKH + dk) * SEQ + s0 + c) = u.v8;
  }
}

// ---------------------------------------------------------------------------
// Flash attention — ROUND 12: round-9 structure (KVBLK=64, 8-wave blocks,
// best known) + P^T staged through a per-wave LDS buffer instead of the
// 16-bpermute shuffle build: lane owns q-row lr, so P^T[lr][keys] is
// written as 4x ds_write_b64 (packed bf16 pairs, XOR-swizzled) and the PV
// B-frag is exactly 2x ds_read_b128 of the same row (same swizzle both
// sides). Same-wave write->read: lgkmcnt-ordered, no barrier. Read pattern
// is byte-identical to the K-frag read (measured 0 conflicts in proj).
// Keeps: swapped QK^T, in-register exp2 softmax, exact defer-rescale,
// O^T accumulation, global LPT work queue.
// grid = 768 persistent blocks, block = 512 (8 waves x 16 q-rows).
// ---------------------------------------------------------------------------
__global__ __launch_bounds__(512, 6) void attn_fwd(
    const bf16* __restrict__ qw, const bf16* __restrict__ kw,
    const bf16* __restrict__ vt, const int* __restrict__ lens,
    const int* __restrict__ perm, int* __restrict__ ctr,
    float* __restrict__ out) {
  __shared__ bf16 ks[64 * 64];
  __shared__ bf16 vs[64 * 64];
  __shared__ bf16 ps[8][16 * 64];  // per-wave P^T[q=16][key=64], 2 KB each
  __shared__ int s_item;
  const int tid = threadIdx.x, lane = tid & 63, w = tid >> 6;  // w = 0..7
  const int lr = lane & 15, lg = lane >> 4;
  const int rsw = (lr & 7) << 4;  // read-side XOR swizzle
  const int srow = tid >> 3;      // 0..63: one staging row per 8 threads
  const int scolb = ((tid & 7) * 16) ^ ((srow & 7) << 4);  // inverse-swz source col
  bf16* const psw = ps[w];

  for (;;) {
    __syncthreads();  // prior item's LDS reads + s_item consumption done
    if (tid == 0) s_item = atomicAdd(ctr, 1);
    __syncthreads();
    const int item = s_item;
    if (item >= NITEMS) return;

    const int b = perm[item >> 8];  // LPT: 256 items per batch, longest first
    const int h = (item >> 4) & 15;
    const int q0 = (item & 15) * 128;
    const int len = lens[b];
    const int ntiles = (len + 63) >> 6;

    const bf16* kbase = kw + (size_t)b * SEQ * DM + h * 64;
    const bf16* vbase = vt + (size_t)(b * NH + h) * DKH * SEQ;
    // Q[q=lr-row of this wave][dk = lg*8.. (+32)] serves as B-frag directly
    const bf16* qbase = qw + ((size_t)b * SEQ + q0 + w * 16 + lr) * DM + h * 64 + lg * 8;
    const bf16x8 aq0 = *(const bf16x8*)(qbase);
    const bf16x8 aq1 = *(const bf16x8*)(qbase + 32);

    f32x4 acc[4];  // O^T: acc[n][j] = O[q=lr][dk = n*16 + lg*4 + j]
#pragma unroll
    for (int n = 0; n < 4; ++n) acc[n] = (f32x4){0.f, 0.f, 0.f, 0.f};
    float mrow = -1e30f, lrow = 0.f;

    for (int t = 0; t < ntiles; ++t) {
      const int k0 = t * 64;
      __syncthreads();  // prior tile's ks/vs reads complete
      // one gload per thread each for K and V (512 thr x 16 B = 8 KB tile)
      gload_lds16((const char*)(kbase + (size_t)(k0 + srow) * DM) + scolb,
                  (char*)ks + tid * 16);
      gload_lds16((const char*)(vbase + (size_t)srow * SEQ + k0) + scolb,
                  (char*)vs + tid * 16);
      __syncthreads();  // vmcnt drained -> tiles readable

      // ---- S^T = K @ Q^T : s[m][j] = S[key = m*16 + lg*4 + j][q = lr] ----
      // (scores already in log2 domain: q pre-scaled by log2e/sqrt(dm))
      f32x4 s[4];
#pragma unroll
      for (int n = 0; n < 4; ++n) s[n] = (f32x4){0.f, 0.f, 0.f, 0.f};
#pragma unroll
      for (int kk = 0; kk < 2; ++kk) {
        const bf16x8 aqk = kk ? aq1 : aq0;
#pragma unroll
        for (int m = 0; m < 4; ++m) {
          bf16x8 ak = *(const bf16x8*)((const char*)ks + (m * 16 + lr) * 128 +
                                       ((kk * 64 + lg * 16) ^ rsw));
          s[m] = __builtin_amdgcn_mfma_f32_16x16x32_bf16(ak, aqk, s[m], 0, 0, 0);
        }
      }
      if (k0 + 64 > len) {  // mask keys >= len (final partial tile only)
#pragma unroll
        for (int m = 0; m < 4; ++m)
#pragma unroll
          for (int j = 0; j < 4; ++j)
            if (k0 + m * 16 + lg * 4 + j >= len) s[m][j] = -1e30f;
      }

      // ---- online softmax (exp2 domain), per-lane scalar state ----
      float tmax = fmaxf(fmaxf(fmaxf(s[0][0], s[0][1]), fmaxf(s[0][2], s[0][3])),
                         fmaxf(fmaxf(s[1][0], s[1][1]), fmaxf(s[1][2], s[1][3])));
      tmax = fmaxf(tmax,
                   fmaxf(fmaxf(fmaxf(s[2][0], s[2][1]), fmaxf(s[2][2], s[2][3])),
                         fmaxf(fmaxf(s[3][0], s[3][1]), fmaxf(s[3][2], s[3][3]))));
      tmax = fmaxf(tmax, __shfl_xor(tmax, 16, 64));
      tmax = fmaxf(tmax, __shfl_xor(tmax, 32, 64));
      if (!__all(tmax <= mrow)) {  // defer-rescale: scl==1 exactly when skipped
        const float mn = fmaxf(mrow, tmax);
        const float scl = exp2f(mrow - mn);
        mrow = mn;
        lrow *= scl;
#pragma unroll
        for (int n = 0; n < 4; ++n) acc[n] *= scl;
      }

      float lsum = 0.f;
#pragma unroll
      for (int m = 0; m < 4; ++m)
#pragma unroll
        for (int j = 0; j < 4; ++j) {
          const float p = exp2f(s[m][j] - mrow);
          s[m][j] = p;
          lsum += p;
        }
      lsum += __shfl_xor(lsum, 16, 64);
      lsum += __shfl_xor(lsum, 32, 64);
      lrow += lsum;

      // ---- pack P to bf16 pairs and write P^T[q=lr] to per-wave LDS ----
      // lane's 16 keys are m*16 + lg*4 + {0..3} -> byte col m*32 + lg*8
#pragma unroll
      for (int m = 0; m < 4; ++m) {
        bf16x2 t0, t1;
        t0[0] = (bf16)s[m][0]; t0[1] = (bf16)s[m][1];
        t1[0] = (bf16)s[m][2]; t1[1] = (bf16)s[m][3];
        u32x2 v2;
        v2[0] = __builtin_bit_cast(u32, t0);
        v2[1] = __builtin_bit_cast(u32, t1);
        *(u32x2*)((char*)psw + lr * 128 + ((m * 32 + lg * 8) ^ rsw)) = v2;
      }

      // ---- PV: O^T += V^T @ P^T ; B-frag = 16B of P^T row lr (same swz) ----
#pragma unroll
      for (int kk = 0; kk < 2; ++kk) {
        const bf16x8 bp = *(const bf16x8*)((const char*)psw + lr * 128 +
                                           ((kk * 64 + lg * 16) ^ rsw));
#pragma unroll
        for (int n = 0; n < 4; ++n) {
          bf16x8 av = *(const bf16x8*)((const char*)vs + (n * 16 + lr) * 128 +
                                       ((kk * 64 + lg * 16) ^ rsw));
          acc[n] = __builtin_amdgcn_mfma_f32_16x16x32_bf16(av, bp, acc[n], 0, 0, 0);
        }
      }
    }

    // ---- epilogue: O = acc / lrow; acc[n][j] is contiguous in dk ----
    const float inv = 1.0f / lrow;
    float* obase = out + ((size_t)b * SEQ + q0 + w * 16 + lr) * DM + h * 64 + lg * 4;
#pragma unroll
    for (int n = 0; n < 4; ++n) {
      f32x4 o = acc[n] * inv;
      *(f32x4*)(obase + n * 16) = o;
    }
  }
}

extern "C" void kernel_launch(void* const* d_in, const int* in_sizes, int n_in,
                              void* d_out, int out_size, void* d_ws, size_t ws_size,
                              hipStream_t stream) {
  const float* Q = (const float*)d_in[0];
  const float* K = (const float*)d_in[1];
  const float* V = (const float*)d_in[2];
  const float* W = (const float*)d_in[3];
  const int* lens = (const int*)d_in[4];
  float* out = (float*)d_out;

  char* ws = (char*)d_ws;
  const size_t seg = (size_t)BS * SEQ * DM * sizeof(bf16);  // 16 MiB
  bf16* qw = (bf16*)(ws);
  bf16* kw = (bf16*)(ws + seg);
  bf16* vw = (bf16*)(ws + 2 * seg);
  bf16* vt = (bf16*)(ws + 3 * seg);
  bf16* Wb = (bf16*)(ws + 4 * seg);             // 2 MiB
  int* perm = (int*)(ws + 4 * seg + 0x200000);  // 16 B
  int* ctr = perm + 4;

  wconv<<<dim3((DM * DM) / (256 * 4)), 256, 0, stream>>>(W, Wb, lens, perm, ctr);
  proj_gemm<<<1536, 256, 0, stream>>>(Q, K, V, Wb, qw, kw, vw);
  vtrans<<<dim3(SEQ / 64, NH, BS), 256, 0, stream>>>(vw, vt);
  attn_fwd<<<768, 512, 0, stream>>>(qw, kw, vt, lens, perm, ctr, out);
}